// Round 6
// baseline (83.676 us; speedup 1.0000x reference)
//
#include <hip/hip_runtime.h>
#include <hip/hip_bf16.h>
#include <math.h>

#define NROWS 16384
#define DIN   784
#define DZ    100
#define NS    10
#define NCT   16           // 16 col-tiles x 16 = 256 cols (200 real + 56 zero pad)
#define KT2   28           // kt padded to 28 so every K-split wave runs 7 uniform steps
#define BND_THR 45.0f

typedef unsigned short ushort_t;
typedef short bf16x8 __attribute__((ext_vector_type(8)));
typedef float f32x4  __attribute__((ext_vector_type(4)));

// ws layout (float offsets):
//  [0..199]   colsum softplus (atomic)   [200] pv log-sum (atomic)   [201] Dkl
//  [208..8047] y2[s][i] = y * log2e      [8064..9063] z[s][d]
//  [16384..]   Wb: bf16 fragment-swizzled W, 28*16*512 ushorts (448 KB)
#define WS_Y2 208
#define WS_Z  8064
#define WS_WB 16384

__device__ __forceinline__ float softplusf(float v) {
    return fmaxf(v, 0.f) + log1pf(__expf(-fabsf(v)));
}
__device__ __forceinline__ unsigned pack2(float lo, float hi) {
    float2 f2; f2.x = lo; f2.y = hi;
    __hip_bfloat162 h2 = __float22bfloat162_rn(f2);
    return *reinterpret_cast<unsigned*>(&h2);
}

// ---- W -> bf16, pre-swizzled to MFMA B-fragment order (kt padded to 28) ----
// Wb[((kt*16 + ct)*64 + l)*8 + j] = W[ct*16 + (l&15)][kt*32 + (l>>4)*8 + j]
__global__ __launch_bounds__(256) void wb2_kernel(
    const float* __restrict__ W0, const float* __restrict__ W1, ushort_t* __restrict__ Wb)
{
    int t = blockIdx.x * 256 + threadIdx.x;
    if (t >= KT2 * NCT * 64) return;
    int kt = t >> 10;
    int r  = t & 1023;
    int ct = r >> 6, l = r & 63;
    int col = ct * 16 + (l & 15);
    int k0  = kt * 32 + (l >> 4) * 8;
    uint4 o = make_uint4(0u, 0u, 0u, 0u);
    if (col < 200 && k0 < DIN) {           // frag-aligned tail & kt>=25 zeroed
        const float* src = (col < 100 ? W0 + (size_t)col * DIN
                                      : W1 + (size_t)(col - 100) * DIN) + k0;
        float4 a = *(const float4*)src;
        float4 b = *(const float4*)(src + 4);
        o.x = pack2(a.x, a.y); o.y = pack2(a.z, a.w);
        o.z = pack2(b.x, b.y); o.w = pack2(b.z, b.w);
    }
    *(uint4*)(Wb + (size_t)t * 8) = o;
}

// ---- MFMA column-sum of softplus(x@W.T + b) ----
// 2048 blocks x 256 thr. Block = (32 rows, 4 col-tiles); its 4 waves K-split
// (wave w does kt = w, w+4, ..., 7 steps). Reg dbuf pinned by sched_barrier(0).
// Partial accs combined via LDS, softplus applied on wave 0 after full-K sum.
__global__ __launch_bounds__(256, 4) void colmean_mfma(
    const float* __restrict__ x, const ushort_t* __restrict__ Wb,
    const float* __restrict__ b0, const float* __restrict__ b1,
    float* __restrict__ ws)
{
    __shared__ float red[2][64][32];       // 16 KB
    const int tid = threadIdx.x;
    const int lane = tid & 63, w = tid >> 6;

    // XCD-bijective swizzle: each XCD gets 256 consecutive logical ids
    // = 64 rowchunks x 4 col-quarters -> the 4 cq-siblings share an XCD L2.
    int b = blockIdx.x;
    int logical = (b & 7) * 256 + (b >> 3);
    const int rowchunk = logical >> 2, cq = logical & 3;
    const int row = rowchunk * 32 + (lane & 15);
    const int kc = lane >> 4;
    const float* xp0 = x + (size_t)row * DIN;
    const float* xp1 = xp0 + (size_t)16 * DIN;

    f32x4 acc[2][4];
#pragma unroll
    for (int rg = 0; rg < 2; ++rg)
#pragma unroll
        for (int jj = 0; jj < 4; ++jj) acc[rg][jj] = (f32x4){0.f, 0.f, 0.f, 0.f};

    float4 aA[2][2], aB[2][2];
    uint4 bA[4], bB[4];

    auto loadA = [&](int kt, float4 (&ar)[2][2]) {
        int k0 = kt * 32 + kc * 8;
        if (k0 + 8 > DIN) k0 = 768;        // junk ok: W frags zero at k>=784
        ar[0][0] = *(const float4*)(xp0 + k0);
        ar[0][1] = *(const float4*)(xp0 + k0 + 4);
        ar[1][0] = *(const float4*)(xp1 + k0);
        ar[1][1] = *(const float4*)(xp1 + k0 + 4);
    };
    auto loadB = [&](int kt, uint4 (&bb)[4]) {
#pragma unroll
        for (int jj = 0; jj < 4; ++jj)
            bb[jj] = *(const uint4*)(Wb + ((size_t)(kt * NCT + cq * 4 + jj) * 64 + lane) * 8);
    };
    auto comp = [&](const float4 (&ar)[2][2], const uint4 (&bb)[4]) {
#pragma unroll
        for (int rg = 0; rg < 2; ++rg) {
            bf16x8 af; unsigned* p = (unsigned*)&af;
            p[0] = pack2(ar[rg][0].x, ar[rg][0].y);
            p[1] = pack2(ar[rg][0].z, ar[rg][0].w);
            p[2] = pack2(ar[rg][1].x, ar[rg][1].y);
            p[3] = pack2(ar[rg][1].z, ar[rg][1].w);
#pragma unroll
            for (int jj = 0; jj < 4; ++jj)
                acc[rg][jj] = __builtin_amdgcn_mfma_f32_16x16x32_bf16(
                    af, *(const bf16x8*)&bb[jj], acc[rg][jj], 0, 0, 0);
        }
    };

    loadA(w, aA); loadB(w, bA);
#pragma unroll
    for (int i = 0; i < 3; ++i) {
        loadA(4 * (2 * i + 1) + w, aB); loadB(4 * (2 * i + 1) + w, bB);
        __builtin_amdgcn_sched_barrier(0);     // pin: prefetch stays above MFMAs
        comp(aA, bA);
        loadA(4 * (2 * i + 2) + w, aA); loadB(4 * (2 * i + 2) + w, bA);
        __builtin_amdgcn_sched_barrier(0);
        comp(aB, bB);
    }
    comp(aA, bA);

    // cross-wave K reduce: w2,w3 -> LDS; w0+=w2, w1+=w3; w1 -> LDS; w0+=w1.
    if (w >= 2) {
#pragma unroll
        for (int rg = 0; rg < 2; ++rg)
#pragma unroll
            for (int jj = 0; jj < 4; ++jj)
#pragma unroll
                for (int r = 0; r < 4; ++r)
                    red[w - 2][lane][rg * 16 + jj * 4 + r] = acc[rg][jj][r];
    }
    __syncthreads();
    if (w < 2) {
#pragma unroll
        for (int rg = 0; rg < 2; ++rg)
#pragma unroll
            for (int jj = 0; jj < 4; ++jj)
#pragma unroll
                for (int r = 0; r < 4; ++r)
                    acc[rg][jj][r] += red[w][lane][rg * 16 + jj * 4 + r];
    }
    __syncthreads();
    if (w == 1) {
#pragma unroll
        for (int rg = 0; rg < 2; ++rg)
#pragma unroll
            for (int jj = 0; jj < 4; ++jj)
#pragma unroll
                for (int r = 0; r < 4; ++r)
                    red[0][lane][rg * 16 + jj * 4 + r] = acc[rg][jj][r];
    }
    __syncthreads();
    if (w == 0) {
#pragma unroll
        for (int jj = 0; jj < 4; ++jj) {
            int j = (cq * 4 + jj) * 16 + (lane & 15);
            float bias = (j < 100) ? b0[j] : ((j < 200) ? b1[j - 100] : 0.f);
            float v = 0.f;
#pragma unroll
            for (int rg = 0; rg < 2; ++rg)
#pragma unroll
                for (int r = 0; r < 4; ++r)
                    v += softplusf(acc[rg][jj][r] + red[0][lane][rg * 16 + jj * 4 + r] + bias);
            v += __shfl_xor(v, 16);
            v += __shfl_xor(v, 32);
            if ((lane >> 4) == 0 && j < 200) atomicAdd(&ws[j], v);
        }
    }
}

// ---- mean/cov, z, Dkl (single block) ----
__global__ __launch_bounds__(256) void middle_kernel(
    const float* __restrict__ eps, float* __restrict__ ws)
{
    __shared__ float red[256];
    const int tid = threadIdx.x;
    float contrib = 0.f;
    if (tid < DZ) {
        const float inv = 1.f / (float)NROWS;
        float mm = ws[tid] * inv;
        float cc = ws[100 + tid] * inv;
        contrib = 0.5f * __logf(cc);
#pragma unroll
        for (int s = 0; s < NS; ++s) {
            float e = eps[s * DZ + tid];
            float zz = mm + cc * e;
            ws[WS_Z + s * DZ + tid] = zz;
            contrib += (0.5f * cc * e * e - 0.5f * zz * zz) * (1.f / NS);
        }
    }
    red[tid] = contrib;
    __syncthreads();
    for (int off = 128; off > 0; off >>= 1) {
        if (tid < off) red[tid] += red[tid + off];
        __syncthreads();
    }
    if (tid == 0) ws[201] = red[0];
}

// ---- y2 = (z @ W2.T + b2) * log2e ----
__global__ __launch_bounds__(256) void y2_kernel(
    const float* __restrict__ W2, const float* __restrict__ b2,
    float* __restrict__ ws)
{
    int wid  = (int)((blockIdx.x * 256 + threadIdx.x) >> 6);
    int lane = threadIdx.x & 63;
    if (wid >= NS * DIN) return;
    int s = wid / DIN, i = wid % DIN;
    const float* zz = ws + WS_Z + s * DZ;
    const float* wr = W2 + (size_t)i * DZ;
    float p = 0.f;
    for (int d = lane; d < DZ; d += 64) p += zz[d] * wr[d];
#pragma unroll
    for (int off = 32; off > 0; off >>= 1) p += __shfl_xor(p, off);
    if (lane == 0) ws[WS_Y2 + wid] = (p + b2[i]) * 1.4426950408889634f;
}

// ---- sum over (b,s) of log(prod_i sigmoid((2x-1)*y) + 1e-3) ----
// MFMA-certified bound: sum_i max(u,0) = 0.5*(n.y + |n|.|y|), u=(1-2x)*y2 (log2 units).
// bnd >= 45 => p < 2^-43 << ulp(0.001)/2 => term == ln(0.001) exactly. 1024 blocks,
// block = one 16-row tile, 4 waves K-split + LDS reduce; fallback for rare rows.
__global__ __launch_bounds__(256, 4) void pv_kernel(
    const float* __restrict__ x, const float* __restrict__ ws, float* __restrict__ out_sum)
{
    __shared__ ushort_t yf[KT2 * 512];     // 28 KB: y2 B-frags (|y| derived by masking)
    __shared__ float red[4][64][8];        // 8 KB
    const int tid = threadIdx.x;
    const int lane = tid & 63, w = tid >> 6;

    for (int idx = tid; idx < KT2 * 64; idx += 256) {
        int kt = idx >> 6, l = idx & 63;
        int ss = l & 15, k0 = kt * 32 + (l >> 4) * 8;
        uint4 o = make_uint4(0u, 0u, 0u, 0u);
        if (ss < NS && k0 < DIN) {
            const float* src = ws + WS_Y2 + ss * DIN + k0;
            float4 a = *(const float4*)src, b2v = *(const float4*)(src + 4);
            o.x = pack2(a.x, a.y); o.y = pack2(a.z, a.w);
            o.z = pack2(b2v.x, b2v.y); o.w = pack2(b2v.z, b2v.w);
        }
        *(uint4*)(yf + (size_t)idx * 8) = o;
    }
    __syncthreads();

    const int tile = blockIdx.x;           // 1024 tiles of 16 rows
    const int row  = tile * 16 + (lane & 15);
    const int kc   = lane >> 4;
    const float* xp = x + (size_t)row * DIN;
    const float L001 = -6.90775527898f;    // ln(0.001f)

    f32x4 acc0 = (f32x4){0.f, 0.f, 0.f, 0.f};
    f32x4 acc1 = (f32x4){0.f, 0.f, 0.f, 0.f};
    float4 aA0, aA1, aB0, aB1;

    auto loadA = [&](int kt, float4& a0, float4& a1) {
        int k0 = kt * 32 + kc * 8;
        if (k0 + 8 > DIN) k0 = 768;        // junk ok: y frags zero at k>=784
        a0 = *(const float4*)(xp + k0);
        a1 = *(const float4*)(xp + k0 + 4);
    };
    auto comp = [&](int kt, const float4& a0, const float4& a1) {
        bf16x8 nf; unsigned* p = (unsigned*)&nf;
        p[0] = pack2(1.f - 2.f * a0.x, 1.f - 2.f * a0.y);
        p[1] = pack2(1.f - 2.f * a0.z, 1.f - 2.f * a0.w);
        p[2] = pack2(1.f - 2.f * a1.x, 1.f - 2.f * a1.y);
        p[3] = pack2(1.f - 2.f * a1.z, 1.f - 2.f * a1.w);
        bf16x8 na; unsigned* q = (unsigned*)&na;
        q[0] = p[0] & 0x7FFF7FFFu; q[1] = p[1] & 0x7FFF7FFFu;
        q[2] = p[2] & 0x7FFF7FFFu; q[3] = p[3] & 0x7FFF7FFFu;
        bf16x8 fy = *(const bf16x8*)(yf + (size_t)kt * 512 + lane * 8);
        bf16x8 fa; unsigned* fq = (unsigned*)&fa; const unsigned* fp = (const unsigned*)&fy;
        fq[0] = fp[0] & 0x7FFF7FFFu; fq[1] = fp[1] & 0x7FFF7FFFu;
        fq[2] = fp[2] & 0x7FFF7FFFu; fq[3] = fp[3] & 0x7FFF7FFFu;
        acc0 = __builtin_amdgcn_mfma_f32_16x16x32_bf16(nf, fy, acc0, 0, 0, 0);
        acc1 = __builtin_amdgcn_mfma_f32_16x16x32_bf16(na, fa, acc1, 0, 0, 0);
    };

    loadA(w, aA0, aA1);
#pragma unroll
    for (int i = 0; i < 3; ++i) {
        loadA(4 * (2 * i + 1) + w, aB0, aB1);
        __builtin_amdgcn_sched_barrier(0);
        comp(4 * (2 * i) + w, aA0, aA1);
        loadA(4 * (2 * i + 2) + w, aA0, aA1);
        __builtin_amdgcn_sched_barrier(0);
        comp(4 * (2 * i + 1) + w, aB0, aB1);
    }
    comp(24 + w, aA0, aA1);

#pragma unroll
    for (int r = 0; r < 4; ++r) {
        red[w][lane][r]     = acc0[r];
        red[w][lane][4 + r] = acc1[r];
    }
    __syncthreads();

    if (w == 0) {
        const int s = lane & 15;
        float bnd[4];
#pragma unroll
        for (int r = 0; r < 4; ++r) {
            float s0 = red[0][lane][r] + red[1][lane][r] + red[2][lane][r] + red[3][lane][r];
            float s1 = red[0][lane][4 + r] + red[1][lane][4 + r]
                     + red[2][lane][4 + r] + red[3][lane][4 + r];
            bnd[r] = 0.5f * (s0 + s1);
        }
        float wsum;
        bool lslow = (s < NS) &&
            (fminf(fminf(bnd[0], bnd[1]), fminf(bnd[2], bnd[3])) < BND_THR);
        unsigned long long m = __ballot(lslow);
        if (m == 0ull) {
            wsum = 160.f * L001;           // 16 rows x 10 samples, all certified
        } else {
            int nslow = 0;
            float slowsum = 0.f;
#pragma unroll
            for (int r = 0; r < 4; ++r) {
                unsigned long long mr = __ballot((s < NS) && (bnd[r] < BND_THR));
                nslow += (int)__popcll(mr);
                while (mr) {
                    int src = (int)__ffsll(mr) - 1; mr &= (mr - 1);
                    int ss = src & 15;
                    int rrow = tile * 16 + (src >> 4) * 4 + r;
                    const float* xq = x + (size_t)rrow * DIN;
                    const float* yq = ws + WS_Y2 + ss * DIN;
                    float a = 0.f;
                    for (int i = lane; i < DIN; i += 64)
                        a -= __builtin_amdgcn_logf(
                            1.f + __builtin_amdgcn_exp2f((1.f - 2.f * xq[i]) * yq[i]));
#pragma unroll
                    for (int off = 32; off > 0; off >>= 1) a += __shfl_xor(a, off);
                    slowsum += __logf(__builtin_amdgcn_exp2f(a) + 0.001f);
                }
            }
            wsum = (float)(160 - nslow) * L001 + slowsum;
        }
        if (lane == 0) atomicAdd(out_sum, wsum);
    }
}

// ---- final scalar ----
__global__ void final_kernel(const float* __restrict__ ws, float* __restrict__ out)
{
    float E = ws[200] * (1.f / ((float)NROWS * (float)NS));
    out[0] = -(E + ws[201]);
}

extern "C" void kernel_launch(void* const* d_in, const int* in_sizes, int n_in,
                              void* d_out, int out_size, void* d_ws, size_t ws_size,
                              hipStream_t stream)
{
    const float* x   = (const float*)d_in[0];
    const float* W0  = (const float*)d_in[1];
    const float* b0  = (const float*)d_in[2];
    const float* W1  = (const float*)d_in[3];
    const float* b1  = (const float*)d_in[4];
    const float* W2  = (const float*)d_in[5];
    const float* b2  = (const float*)d_in[6];
    const float* eps = (const float*)d_in[7];
    float* out = (float*)d_out;
    float* ws  = (float*)d_ws;
    ushort_t* Wb = (ushort_t*)(ws + WS_WB);

    hipMemsetAsync(ws, 0, 256 * sizeof(float), stream);
    wb2_kernel<<<(KT2 * NCT * 64 + 255) / 256, 256, 0, stream>>>(W0, W1, Wb);
    colmean_mfma<<<2048, 256, 0, stream>>>(x, Wb, b0, b1, ws);
    middle_kernel<<<1, 256, 0, stream>>>(eps, ws);
    y2_kernel<<<(NS * DIN * 64) / 256, 256, 0, stream>>>(W2, b2, ws);
    pv_kernel<<<1024, 256, 0, stream>>>(x, ws, ws + 200);
    final_kernel<<<1, 1, 0, stream>>>(ws, out);
}